// Round 21
// baseline (231.016 us; speedup 1.0000x reference)
//
#include <hip/hip_runtime.h>
#include <hip/hip_bf16.h>

// QuantiZ: e = codebook[4096,1024] @ proj_w[256,1024]^T + proj_b
//          zidx[t] = argmin_k ||z_t - e_k||, quant[t] = e[zidx[t]]
// d_out FLOAT32: [ zidx as float (32768) | quant (32768*256) ].
// Score GEMM: split-bf16 3-term (hi*hi + hi*lo + lo*hi), 16x16x32 MFMA.
// R21: score_mfma = exact R18/R20 (best, 177us). proj_gemm -> 1024 threads
//      (4 waves/SIMD latency hiding; acc 1x4; broadcast A + b128 B reads).

#define K_CODES 4096
#define CDIM    256
#define IDIM    1024
#define NTOK    32768

typedef __attribute__((ext_vector_type(8))) short short8;
typedef __attribute__((ext_vector_type(4))) float f32x4;

__device__ __forceinline__ unsigned short f32_to_bf16_rne(float f) {
  union { float f; unsigned int u; } x; x.f = f;
  unsigned int r = x.u + 0x7FFFu + ((x.u >> 16) & 1u);
  return (unsigned short)(r >> 16);
}
__device__ __forceinline__ float bf16_to_f32(unsigned short h) {
  union { unsigned int u; float f; } x; x.u = ((unsigned int)h) << 16;
  return x.f;
}

// ---- Kernel A: e = cb @ pw^T + pb (f32 64x64 tile, 1024 thr) + Ect + e2p ---
// LDS tiles k-major [32][68]; acc 1x4 per thread (ty 0..63 rows).
// Ect layout: frag(kb 0..15, ct 0..255) = 1024 B at (kb*256+ct)*1024,
// lane lf = g*16 + cl holds k-octet g of code ct*16+cl; kb0-7 hi, 8-15 lo.
// e2p[chunk 0..3][row]: partial sum of e^2 over cols chunk*64..chunk*64+63.
extern "C" __global__ __launch_bounds__(1024)
void proj_gemm(const float* __restrict__ cb, const float* __restrict__ pw,
               const float* __restrict__ pb, float* __restrict__ e,
               unsigned short* __restrict__ Ect, float* __restrict__ e2p) {
  __shared__ float As[32][68];   // [kk][row]
  __shared__ float Bs[32][68];
  const int tid = threadIdx.x;
  const int tx = tid & 15, ty = tid >> 4;   // ty 0..63
  const int m0 = blockIdx.y << 6;
  const int n0 = blockIdx.x << 6;
  const int c2 = (tid & 15) << 1;           // staging cols c2, c2+1
  float acc[4] = {};
  for (int k0 = 0; k0 < IDIM; k0 += 32) {
    const float2 a0 = *(const float2*)&cb[(size_t)(m0 + ty) * IDIM + k0 + c2];
    const float2 b0 = *(const float2*)&pw[(size_t)(n0 + ty) * IDIM + k0 + c2];
    __syncthreads();
    As[c2][ty] = a0.x; As[c2+1][ty] = a0.y;
    Bs[c2][ty] = b0.x; Bs[c2+1][ty] = b0.y;
    __syncthreads();
    #pragma unroll
    for (int kk = 0; kk < 32; ++kk) {
      const float  a  = As[kk][ty];
      const float4 bv = *(const float4*)&Bs[kk][tx*4];
      acc[0] += a * bv.x; acc[1] += a * bv.y;
      acc[2] += a * bv.z; acc[3] += a * bv.w;
    }
  }
  // epilogue: write e (f32), fragment-linear hi/lo bf16 Ect, e2 partials
  const int col0 = n0 + tx*4;
  const int kb   = col0 >> 5;
  const int g    = (col0 >> 3) & 3;
  const int half = (col0 >> 2) & 1;
  const int row  = m0 + ty;
  float vv[4];
  unsigned short h4[4], l4[4];
  #pragma unroll
  for (int j = 0; j < 4; ++j) {
    vv[j] = acc[j] + pb[col0 + j];
    h4[j] = f32_to_bf16_rne(vv[j]);
    l4[j] = f32_to_bf16_rne(vv[j] - bf16_to_f32(h4[j]));
  }
  *(float4*)&e[(size_t)row * CDIM + col0] = *(float4*)vv;
  const int ct = row >> 4, cl = row & 15;
  const size_t fi = ((size_t)(kb      * 256 + ct) * 64 + g*16 + cl) * 8 + half*4;
  const size_t fo = ((size_t)((kb+8)  * 256 + ct) * 64 + g*16 + cl) * 8 + half*4;
  *(ushort4*)&Ect[fi] = *(ushort4*)h4;
  *(ushort4*)&Ect[fo] = *(ushort4*)l4;
  float p2 = vv[0]*vv[0] + vv[1]*vv[1] + vv[2]*vv[2] + vv[3]*vv[3];
  #pragma unroll
  for (int m = 1; m < 16; m <<= 1) p2 += __shfl_xor(p2, m, 64);
  if (tx == 0) e2p[(size_t)blockIdx.x * K_CODES + row] = p2;
}

// ---------------- Kernel B: MFMA score + argmin + fused gather --------------
// (exact R18/R20 structure) 128 tokens/block, 8 waves = 2 tg x 4 cg.
// Wave = 64 tok x 64 codes (i in 4, jj in 4). Z: 128 frag-linear LDS frags.
// e2 read as sum of 4 deterministic partials.
extern "C" __global__ __launch_bounds__(512, 2)
void score_mfma(const float* __restrict__ z, const unsigned short* __restrict__ Ect,
                const float* __restrict__ e2p, const float* __restrict__ eg,
                float* __restrict__ zidx_f, float* __restrict__ quant) {
  extern __shared__ __align__(16) char smem[];   // 128K Z + 4K red + 512 idx
  char* Zb = smem;

  const int tid = threadIdx.x;
  const int l   = tid & 63;
  const int w   = tid >> 6;          // wave 0..7
  const int tg  = w >> 2;            // token group 0..1
  const int cg  = w & 3;             // code group 0..3
  const int t0  = blockIdx.x << 7;   // 128 tokens per block

  // ---- stage Z (hi/lo bf16) into fragment-linear LDS frags ----
  #pragma unroll
  for (int rr = 0; rr < 2; ++rr) {
    const int r  = rr*64 + (tid >> 3);    // token row 0..127
    const int cq = tid & 7;               // col base cq*32
    const int i8 = r >> 4;                // frag i 0..7
    const int rl = (r & 15) << 4;         // lane-slot byte within frag
    #pragma unroll
    for (int it = 0; it < 4; ++it) {
      const int col = cq*32 + it*8;       // g = it, kb_hi = cq, kb_lo = cq+8
      const float4 v0 = *(const float4*)&z[(size_t)(t0 + r) * CDIM + col];
      const float4 v1 = *(const float4*)&z[(size_t)(t0 + r) * CDIM + col + 4];
      float vv[8] = {v0.x,v0.y,v0.z,v0.w,v1.x,v1.y,v1.z,v1.w};
      unsigned int hp[4], lp[4];
      #pragma unroll
      for (int c = 0; c < 4; ++c) {
        unsigned short h0 = f32_to_bf16_rne(vv[2*c]);
        unsigned short h1 = f32_to_bf16_rne(vv[2*c+1]);
        unsigned short l0 = f32_to_bf16_rne(vv[2*c]   - bf16_to_f32(h0));
        unsigned short l1 = f32_to_bf16_rne(vv[2*c+1] - bf16_to_f32(h1));
        hp[c] = (unsigned int)h0 | ((unsigned int)h1 << 16);
        lp[c] = (unsigned int)l0 | ((unsigned int)l1 << 16);
      }
      const int lane_b = it*256 + rl;     // (g*16 + (r&15)) * 16
      *(uint4*)(Zb + (size_t)(i8*16 + cq    ) * 1024 + lane_b) = *(uint4*)hp;
      *(uint4*)(Zb + (size_t)(i8*16 + cq + 8) * 1024 + lane_b) = *(uint4*)lp;
    }
  }
  __syncthreads();   // Z ready; no further barriers until final reduce

  float bestv[4][4];
  int   besti[4][4];
  #pragma unroll
  for (int i = 0; i < 4; ++i)
    #pragma unroll
    for (int r = 0; r < 4; ++r) { bestv[i][r] = 3.4e38f; besti[i][r] = 0; }

  const int cl = l & 15;
  const int g  = l >> 4;

  // Ect frag(kb, ct) at (kb*256+ct)*1024; wave's ct = cc*16 + cg*4 + jj
  const char* ebase = (const char*)Ect + (size_t)l * 16 + (size_t)cg * 4096;
  // A frags for this wave: frag index (tg*4 + i)*16 + kb
  const char* Zl    = Zb + (size_t)l * 16 + (size_t)tg * 65536;

  // pipeline registers (depth-1), carried across cc
  short8 aHc[4], aLc[4], bHc[4], bLc[4];
  #pragma unroll
  for (int i = 0; i < 4; ++i) {
    aHc[i] = *(const short8*)(Zl + (size_t)(i*16 + 0) * 1024);
    aLc[i] = *(const short8*)(Zl + (size_t)(i*16 + 8) * 1024);
  }
  #pragma unroll
  for (int jj = 0; jj < 4; ++jj) {
    bHc[jj] = *(const short8*)(ebase + (size_t)0 * 262144 + jj * 1024);
    bLc[jj] = *(const short8*)(ebase + (size_t)8 * 262144 + jj * 1024);
  }

  for (int cc = 0; cc < 16; ++cc) {              // 256-code chunks
    const char* ecc  = ebase + (size_t)cc * 16384;
    const char* eccn = ebase + (size_t)((cc + 1) & 15) * 16384;

    f32x4 acc[4][4];
    #pragma unroll
    for (int i = 0; i < 4; ++i)
      #pragma unroll
      for (int jj = 0; jj < 4; ++jj) acc[i][jj] = (f32x4){0.f,0.f,0.f,0.f};

    float e2v[4];
    #pragma unroll
    for (int jj = 0; jj < 4; ++jj) {
      const int code = cc*256 + cg*64 + jj*16 + cl;
      e2v[jj] = e2p[code] + e2p[K_CODES + code]
              + e2p[2*K_CODES + code] + e2p[3*K_CODES + code];
    }

    #pragma unroll
    for (int kw = 0; kw < 8; ++kw) {
      // issue next step's loads (B global first, then A ds)
      short8 aHn[4], aLn[4], bHn[4], bLn[4];
      {
        const char* bsrc = (kw < 7) ? ecc : eccn;
        const int kwn = (kw + 1) & 7;
        #pragma unroll
        for (int jj = 0; jj < 4; ++jj) {
          bHn[jj] = *(const short8*)(bsrc + (size_t)(kwn    ) * 262144 + jj * 1024);
          bLn[jj] = *(const short8*)(bsrc + (size_t)(kwn + 8) * 262144 + jj * 1024);
        }
        #pragma unroll
        for (int i = 0; i < 4; ++i) {
          aHn[i] = *(const short8*)(Zl + (size_t)(i*16 + kwn    ) * 1024);
          aLn[i] = *(const short8*)(Zl + (size_t)(i*16 + kwn + 8) * 1024);
        }
      }
      __builtin_amdgcn_s_setprio(1);   // fence bounds hoist window (R15)
      #pragma unroll
      for (int i = 0; i < 4; ++i)
        #pragma unroll
        for (int jj = 0; jj < 4; ++jj)
          acc[i][jj] = __builtin_amdgcn_mfma_f32_16x16x32_bf16(aHc[i], bHc[jj], acc[i][jj], 0, 0, 0);
      #pragma unroll
      for (int i = 0; i < 4; ++i)
        #pragma unroll
        for (int jj = 0; jj < 4; ++jj)
          acc[i][jj] = __builtin_amdgcn_mfma_f32_16x16x32_bf16(aHc[i], bLc[jj], acc[i][jj], 0, 0, 0);
      #pragma unroll
      for (int i = 0; i < 4; ++i)
        #pragma unroll
        for (int jj = 0; jj < 4; ++jj)
          acc[i][jj] = __builtin_amdgcn_mfma_f32_16x16x32_bf16(aLc[i], bHc[jj], acc[i][jj], 0, 0, 0);
      __builtin_amdgcn_s_setprio(0);
      // rename pipeline regs
      #pragma unroll
      for (int i = 0; i < 4; ++i) { aHc[i] = aHn[i]; aLc[i] = aLn[i]; }
      #pragma unroll
      for (int jj = 0; jj < 4; ++jj) { bHc[jj] = bHn[jj]; bLc[jj] = bLn[jj]; }
    }
    // epilogue: scores -> running argmin (codes ascend: cc outer, jj inner)
    #pragma unroll
    for (int jj = 0; jj < 4; ++jj) {
      const int code = cc*256 + cg*64 + jj*16 + cl;
      #pragma unroll
      for (int i = 0; i < 4; ++i)
        #pragma unroll
        for (int r = 0; r < 4; ++r) {
          const float sc = e2v[jj] - 2.0f * acc[i][jj][r];
          if (sc < bestv[i][r]) { bestv[i][r] = sc; besti[i][r] = code; }
        }
    }
  }

  // ---- final argmin reduce: 16 code-lanes, then 4 cg waves via LDS ----
  struct RP { float v; int i; };
  RP*  red    = (RP*)(smem + 131072);          // [128][4]
  int* sh_idx = (int*)(smem + 131072 + 4096);  // [128]
  #pragma unroll
  for (int i = 0; i < 4; ++i)
    #pragma unroll
    for (int r = 0; r < 4; ++r) {
      float v = bestv[i][r]; int bi = besti[i][r];
      #pragma unroll
      for (int m = 1; m < 16; m <<= 1) {
        const float ov = __shfl_xor(v, m, 64);
        const int   oi = __shfl_xor(bi, m, 64);
        if (ov < v || (ov == v && oi < bi)) { v = ov; bi = oi; }
      }
      if (cl == 0) {                 // lanes 0,16,32,48 own token tg*64+i*16+g*4+r
        const int tl = tg*64 + i*16 + g*4 + r;
        red[tl*4 + cg].v = v; red[tl*4 + cg].i = bi;
      }
    }
  __syncthreads();
  if (tid < 128) {
    float v = red[tid*4].v; int bi = red[tid*4].i;
    #pragma unroll
    for (int x = 1; x < 4; ++x) {
      const float ov = red[tid*4 + x].v; const int oi = red[tid*4 + x].i;
      if (ov < v || (ov == v && oi < bi)) { v = ov; bi = oi; }
    }
    zidx_f[t0 + tid] = (float)bi;
    sh_idx[tid] = bi;
  }
  __syncthreads();

  // ---- fused gather: quant[t] = e[idx[t]] (f32, e is L2-resident) ----
  #pragma unroll
  for (int rr = 0; rr < 2; ++rr) {
    const int r   = rr*64 + (tid >> 3);    // token row 0..127
    const int cq  = (tid & 7) << 5;        // col base 0..224
    const int idx = sh_idx[r];
    #pragma unroll
    for (int it = 0; it < 4; ++it) {
      const float4 v0 = *(const float4*)&eg[(size_t)idx * CDIM + cq + it*8];
      const float4 v1 = *(const float4*)&eg[(size_t)idx * CDIM + cq + it*8 + 4];
      *(float4*)&quant[(size_t)(t0 + r) * CDIM + cq + it*8]     = v0;
      *(float4*)&quant[(size_t)(t0 + r) * CDIM + cq + it*8 + 4] = v1;
    }
  }
}

// ---------------- launch ----------------------------------------------------
extern "C" void kernel_launch(void* const* d_in, const int* in_sizes, int n_in,
                              void* d_out, int out_size, void* d_ws, size_t ws_size,
                              hipStream_t stream) {
  const float* encode = (const float*)d_in[0];
  const float* cb     = (const float*)d_in[1];
  const float* pw     = (const float*)d_in[2];
  const float* pb     = (const float*)d_in[3];

  float* e   = (float*)d_ws;                              // 4 MB
  float* e2p = e + (size_t)K_CODES * CDIM;                // 64 KB (4 partials)
  unsigned short* Ect = (unsigned short*)(e2p + 4*K_CODES); // 4 MB frag-linear

  float* out     = (float*)d_out;
  float* zidx_f  = out;
  float* quant_f = out + NTOK;

  (void)hipFuncSetAttribute((const void*)score_mfma,
                            hipFuncAttributeMaxDynamicSharedMemorySize, 135680);

  proj_gemm<<<dim3(CDIM/64, K_CODES/64), 1024, 0, stream>>>(cb, pw, pb, e, Ect, e2p);
  score_mfma<<<NTOK/128, 512, 135680, stream>>>(encode, Ect, e2p, e, zidx_f, quant_f);
}

// Round 22
// 212.068 us; speedup vs baseline: 1.0893x; 1.0893x over previous
//
#include <hip/hip_runtime.h>
#include <hip/hip_bf16.h>

// QuantiZ: e = codebook[4096,1024] @ proj_w[256,1024]^T + proj_b
//          zidx[t] = argmin_k ||z_t - e_k||, quant[t] = e[zidx[t]]
// d_out FLOAT32: [ zidx as float (32768) | quant (32768*256) ].
// Score GEMM: split-bf16 3-term (hi*hi + hi*lo + lo*hi), 16x16x32 MFMA.
// R22: score_mfma = exact R18/R20 (best, ~177us). proj_gemm: in-block
//      split-K — 2 K-groups x 256 thr, each acc4x4 (16 FMA : 2 LDS reads)
//      over K=512, deterministic LDS combine + R16/R20 epilogue.

#define K_CODES 4096
#define CDIM    256
#define IDIM    1024
#define NTOK    32768

typedef __attribute__((ext_vector_type(8))) short short8;
typedef __attribute__((ext_vector_type(4))) float f32x4;

__device__ __forceinline__ unsigned short f32_to_bf16_rne(float f) {
  union { float f; unsigned int u; } x; x.f = f;
  unsigned int r = x.u + 0x7FFFu + ((x.u >> 16) & 1u);
  return (unsigned short)(r >> 16);
}
__device__ __forceinline__ float bf16_to_f32(unsigned short h) {
  union { unsigned int u; float f; } x; x.u = ((unsigned int)h) << 16;
  return x.f;
}

// ---- Kernel A: e = cb @ pw^T + pb (64x64 tile, in-block split-K) -----------
// 512 thr = 2 K-groups x 256. Each group: k-major LDS tiles [32][68],
// acc 4x4/thread over K=512. Combine: kg1 -> LDS, kg0 adds (deterministic),
// kg0 epilogue writes e (f32), fragment-linear hi/lo bf16 Ect, e2p partials.
// Ect layout: frag(kb 0..15, ct 0..255) = 1024 B at (kb*256+ct)*1024,
// lane lf = g*16 + cl holds k-octet g of code ct*16+cl; kb0-7 hi, 8-15 lo.
extern "C" __global__ __launch_bounds__(512)
void proj_gemm(const float* __restrict__ cb, const float* __restrict__ pw,
               const float* __restrict__ pb, float* __restrict__ e,
               unsigned short* __restrict__ Ect, float* __restrict__ e2p) {
  __shared__ float As[2][32][68];   // [kg][kk][row]
  __shared__ float Bs[2][32][68];
  const int tid = threadIdx.x;
  const int kg  = tid >> 8;                 // K-group 0/1
  const int t   = tid & 255;
  const int tx  = t & 15, ty = t >> 4;      // 16x16 -> acc 4x4
  const int m0  = blockIdx.y << 6;
  const int n0  = blockIdx.x << 6;
  const int r   = t >> 2;                   // staging row 0..63
  const int c8  = (t & 3) << 3;             // staging col 0,8,16,24
  float acc[4][4] = {};
  for (int k0s = 0; k0s < 16; ++k0s) {      // 16 steps x 32 k per group
    const int k0 = kg*512 + k0s*32;
    float4 a0 = *(const float4*)&cb[(size_t)(m0 + r) * IDIM + k0 + c8];
    float4 a1 = *(const float4*)&cb[(size_t)(m0 + r) * IDIM + k0 + c8 + 4];
    float4 b0 = *(const float4*)&pw[(size_t)(n0 + r) * IDIM + k0 + c8];
    float4 b1 = *(const float4*)&pw[(size_t)(n0 + r) * IDIM + k0 + c8 + 4];
    __syncthreads();
    As[kg][c8+0][r]=a0.x; As[kg][c8+1][r]=a0.y; As[kg][c8+2][r]=a0.z; As[kg][c8+3][r]=a0.w;
    As[kg][c8+4][r]=a1.x; As[kg][c8+5][r]=a1.y; As[kg][c8+6][r]=a1.z; As[kg][c8+7][r]=a1.w;
    Bs[kg][c8+0][r]=b0.x; Bs[kg][c8+1][r]=b0.y; Bs[kg][c8+2][r]=b0.z; Bs[kg][c8+3][r]=b0.w;
    Bs[kg][c8+4][r]=b1.x; Bs[kg][c8+5][r]=b1.y; Bs[kg][c8+6][r]=b1.z; Bs[kg][c8+7][r]=b1.w;
    __syncthreads();
    #pragma unroll
    for (int kk = 0; kk < 32; ++kk) {
      const float4 av = *(const float4*)&As[kg][kk][ty*4];
      const float4 bv = *(const float4*)&Bs[kg][kk][tx*4];
      const float a4[4] = {av.x, av.y, av.z, av.w};
      const float b4[4] = {bv.x, bv.y, bv.z, bv.w};
      #pragma unroll
      for (int i = 0; i < 4; ++i)
        #pragma unroll
        for (int j = 0; j < 4; ++j)
          acc[i][j] += a4[i] * b4[j];
    }
  }
  // combine the two K-halves (deterministic: acc0 + acc1)
  float* Cb = (float*)As;                   // 16 KB alias, tiles dead
  __syncthreads();
  if (kg == 1) {
    #pragma unroll
    for (int i = 0; i < 4; ++i)
      *(float4*)&Cb[(ty*4 + i) * 64 + tx*4] = *(float4*)&acc[i][0];
  }
  __syncthreads();
  if (kg == 0) {
    const int col0 = n0 + tx*4;
    const int kb   = col0 >> 5;
    const int g    = (col0 >> 3) & 3;
    const int half = (col0 >> 2) & 1;
    float p2[4];
    #pragma unroll
    for (int i = 0; i < 4; ++i) {
      const float4 o = *(const float4*)&Cb[(ty*4 + i) * 64 + tx*4];
      const int row = m0 + ty*4 + i;
      float vv[4];
      unsigned short h4[4], l4[4];
      const float o4[4] = {o.x, o.y, o.z, o.w};
      #pragma unroll
      for (int j = 0; j < 4; ++j) {
        vv[j] = acc[i][j] + o4[j] + pb[col0 + j];
        h4[j] = f32_to_bf16_rne(vv[j]);
        l4[j] = f32_to_bf16_rne(vv[j] - bf16_to_f32(h4[j]));
      }
      *(float4*)&e[(size_t)row * CDIM + col0] = *(float4*)vv;
      const int ct = row >> 4, cl = row & 15;
      const size_t fi = ((size_t)(kb      * 256 + ct) * 64 + g*16 + cl) * 8 + half*4;
      const size_t fo = ((size_t)((kb+8)  * 256 + ct) * 64 + g*16 + cl) * 8 + half*4;
      *(ushort4*)&Ect[fi] = *(ushort4*)h4;
      *(ushort4*)&Ect[fo] = *(ushort4*)l4;
      p2[i] = vv[0]*vv[0] + vv[1]*vv[1] + vv[2]*vv[2] + vv[3]*vv[3];
    }
    // deterministic 16-lane (tx) reduction; lanes ty*16..ty*16+15 in-group
    #pragma unroll
    for (int m = 1; m < 16; m <<= 1) {
      #pragma unroll
      for (int i = 0; i < 4; ++i) p2[i] += __shfl_xor(p2[i], m, 64);
    }
    if (tx == 0) {
      #pragma unroll
      for (int i = 0; i < 4; ++i)
        e2p[(size_t)blockIdx.x * K_CODES + m0 + ty*4 + i] = p2[i];
    }
  }
}

// ---------------- Kernel B: MFMA score + argmin + fused gather --------------
// (exact R18/R20 structure) 128 tokens/block, 8 waves = 2 tg x 4 cg.
// Wave = 64 tok x 64 codes (i in 4, jj in 4). Z: 128 frag-linear LDS frags.
// e2 read as sum of 4 deterministic partials.
extern "C" __global__ __launch_bounds__(512, 2)
void score_mfma(const float* __restrict__ z, const unsigned short* __restrict__ Ect,
                const float* __restrict__ e2p, const float* __restrict__ eg,
                float* __restrict__ zidx_f, float* __restrict__ quant) {
  extern __shared__ __align__(16) char smem[];   // 128K Z + 4K red + 512 idx
  char* Zb = smem;

  const int tid = threadIdx.x;
  const int l   = tid & 63;
  const int w   = tid >> 6;          // wave 0..7
  const int tg  = w >> 2;            // token group 0..1
  const int cg  = w & 3;             // code group 0..3
  const int t0  = blockIdx.x << 7;   // 128 tokens per block

  // ---- stage Z (hi/lo bf16) into fragment-linear LDS frags ----
  #pragma unroll
  for (int rr = 0; rr < 2; ++rr) {
    const int r  = rr*64 + (tid >> 3);    // token row 0..127
    const int cq = tid & 7;               // col base cq*32
    const int i8 = r >> 4;                // frag i 0..7
    const int rl = (r & 15) << 4;         // lane-slot byte within frag
    #pragma unroll
    for (int it = 0; it < 4; ++it) {
      const int col = cq*32 + it*8;       // g = it, kb_hi = cq, kb_lo = cq+8
      const float4 v0 = *(const float4*)&z[(size_t)(t0 + r) * CDIM + col];
      const float4 v1 = *(const float4*)&z[(size_t)(t0 + r) * CDIM + col + 4];
      float vv[8] = {v0.x,v0.y,v0.z,v0.w,v1.x,v1.y,v1.z,v1.w};
      unsigned int hp[4], lp[4];
      #pragma unroll
      for (int c = 0; c < 4; ++c) {
        unsigned short h0 = f32_to_bf16_rne(vv[2*c]);
        unsigned short h1 = f32_to_bf16_rne(vv[2*c+1]);
        unsigned short l0 = f32_to_bf16_rne(vv[2*c]   - bf16_to_f32(h0));
        unsigned short l1 = f32_to_bf16_rne(vv[2*c+1] - bf16_to_f32(h1));
        hp[c] = (unsigned int)h0 | ((unsigned int)h1 << 16);
        lp[c] = (unsigned int)l0 | ((unsigned int)l1 << 16);
      }
      const int lane_b = it*256 + rl;     // (g*16 + (r&15)) * 16
      *(uint4*)(Zb + (size_t)(i8*16 + cq    ) * 1024 + lane_b) = *(uint4*)hp;
      *(uint4*)(Zb + (size_t)(i8*16 + cq + 8) * 1024 + lane_b) = *(uint4*)lp;
    }
  }
  __syncthreads();   // Z ready; no further barriers until final reduce

  float bestv[4][4];
  int   besti[4][4];
  #pragma unroll
  for (int i = 0; i < 4; ++i)
    #pragma unroll
    for (int r = 0; r < 4; ++r) { bestv[i][r] = 3.4e38f; besti[i][r] = 0; }

  const int cl = l & 15;
  const int g  = l >> 4;

  // Ect frag(kb, ct) at (kb*256+ct)*1024; wave's ct = cc*16 + cg*4 + jj
  const char* ebase = (const char*)Ect + (size_t)l * 16 + (size_t)cg * 4096;
  // A frags for this wave: frag index (tg*4 + i)*16 + kb
  const char* Zl    = Zb + (size_t)l * 16 + (size_t)tg * 65536;

  // pipeline registers (depth-1), carried across cc
  short8 aHc[4], aLc[4], bHc[4], bLc[4];
  #pragma unroll
  for (int i = 0; i < 4; ++i) {
    aHc[i] = *(const short8*)(Zl + (size_t)(i*16 + 0) * 1024);
    aLc[i] = *(const short8*)(Zl + (size_t)(i*16 + 8) * 1024);
  }
  #pragma unroll
  for (int jj = 0; jj < 4; ++jj) {
    bHc[jj] = *(const short8*)(ebase + (size_t)0 * 262144 + jj * 1024);
    bLc[jj] = *(const short8*)(ebase + (size_t)8 * 262144 + jj * 1024);
  }

  for (int cc = 0; cc < 16; ++cc) {              // 256-code chunks
    const char* ecc  = ebase + (size_t)cc * 16384;
    const char* eccn = ebase + (size_t)((cc + 1) & 15) * 16384;

    f32x4 acc[4][4];
    #pragma unroll
    for (int i = 0; i < 4; ++i)
      #pragma unroll
      for (int jj = 0; jj < 4; ++jj) acc[i][jj] = (f32x4){0.f,0.f,0.f,0.f};

    float e2v[4];
    #pragma unroll
    for (int jj = 0; jj < 4; ++jj) {
      const int code = cc*256 + cg*64 + jj*16 + cl;
      e2v[jj] = e2p[code] + e2p[K_CODES + code]
              + e2p[2*K_CODES + code] + e2p[3*K_CODES + code];
    }

    #pragma unroll
    for (int kw = 0; kw < 8; ++kw) {
      // issue next step's loads (B global first, then A ds)
      short8 aHn[4], aLn[4], bHn[4], bLn[4];
      {
        const char* bsrc = (kw < 7) ? ecc : eccn;
        const int kwn = (kw + 1) & 7;
        #pragma unroll
        for (int jj = 0; jj < 4; ++jj) {
          bHn[jj] = *(const short8*)(bsrc + (size_t)(kwn    ) * 262144 + jj * 1024);
          bLn[jj] = *(const short8*)(bsrc + (size_t)(kwn + 8) * 262144 + jj * 1024);
        }
        #pragma unroll
        for (int i = 0; i < 4; ++i) {
          aHn[i] = *(const short8*)(Zl + (size_t)(i*16 + kwn    ) * 1024);
          aLn[i] = *(const short8*)(Zl + (size_t)(i*16 + kwn + 8) * 1024);
        }
      }
      __builtin_amdgcn_s_setprio(1);   // fence bounds hoist window (R15)
      #pragma unroll
      for (int i = 0; i < 4; ++i)
        #pragma unroll
        for (int jj = 0; jj < 4; ++jj)
          acc[i][jj] = __builtin_amdgcn_mfma_f32_16x16x32_bf16(aHc[i], bHc[jj], acc[i][jj], 0, 0, 0);
      #pragma unroll
      for (int i = 0; i < 4; ++i)
        #pragma unroll
        for (int jj = 0; jj < 4; ++jj)
          acc[i][jj] = __builtin_amdgcn_mfma_f32_16x16x32_bf16(aHc[i], bLc[jj], acc[i][jj], 0, 0, 0);
      #pragma unroll
      for (int i = 0; i < 4; ++i)
        #pragma unroll
        for (int jj = 0; jj < 4; ++jj)
          acc[i][jj] = __builtin_amdgcn_mfma_f32_16x16x32_bf16(aLc[i], bHc[jj], acc[i][jj], 0, 0, 0);
      __builtin_amdgcn_s_setprio(0);
      // rename pipeline regs
      #pragma unroll
      for (int i = 0; i < 4; ++i) { aHc[i] = aHn[i]; aLc[i] = aLn[i]; }
      #pragma unroll
      for (int jj = 0; jj < 4; ++jj) { bHc[jj] = bHn[jj]; bLc[jj] = bLn[jj]; }
    }
    // epilogue: scores -> running argmin (codes ascend: cc outer, jj inner)
    #pragma unroll
    for (int jj = 0; jj < 4; ++jj) {
      const int code = cc*256 + cg*64 + jj*16 + cl;
      #pragma unroll
      for (int i = 0; i < 4; ++i)
        #pragma unroll
        for (int r = 0; r < 4; ++r) {
          const float sc = e2v[jj] - 2.0f * acc[i][jj][r];
          if (sc < bestv[i][r]) { bestv[i][r] = sc; besti[i][r] = code; }
        }
    }
  }

  // ---- final argmin reduce: 16 code-lanes, then 4 cg waves via LDS ----
  struct RP { float v; int i; };
  RP*  red    = (RP*)(smem + 131072);          // [128][4]
  int* sh_idx = (int*)(smem + 131072 + 4096);  // [128]
  #pragma unroll
  for (int i = 0; i < 4; ++i)
    #pragma unroll
    for (int r = 0; r < 4; ++r) {
      float v = bestv[i][r]; int bi = besti[i][r];
      #pragma unroll
      for (int m = 1; m < 16; m <<= 1) {
        const float ov = __shfl_xor(v, m, 64);
        const int   oi = __shfl_xor(bi, m, 64);
        if (ov < v || (ov == v && oi < bi)) { v = ov; bi = oi; }
      }
      if (cl == 0) {                 // lanes 0,16,32,48 own token tg*64+i*16+g*4+r
        const int tl = tg*64 + i*16 + g*4 + r;
        red[tl*4 + cg].v = v; red[tl*4 + cg].i = bi;
      }
    }
  __syncthreads();
  if (tid < 128) {
    float v = red[tid*4].v; int bi = red[tid*4].i;
    #pragma unroll
    for (int x = 1; x < 4; ++x) {
      const float ov = red[tid*4 + x].v; const int oi = red[tid*4 + x].i;
      if (ov < v || (ov == v && oi < bi)) { v = ov; bi = oi; }
    }
    zidx_f[t0 + tid] = (float)bi;
    sh_idx[tid] = bi;
  }
  __syncthreads();

  // ---- fused gather: quant[t] = e[idx[t]] (f32, e is L2-resident) ----
  #pragma unroll
  for (int rr = 0; rr < 2; ++rr) {
    const int r   = rr*64 + (tid >> 3);    // token row 0..127
    const int cq  = (tid & 7) << 5;        // col base 0..224
    const int idx = sh_idx[r];
    #pragma unroll
    for (int it = 0; it < 4; ++it) {
      const float4 v0 = *(const float4*)&eg[(size_t)idx * CDIM + cq + it*8];
      const float4 v1 = *(const float4*)&eg[(size_t)idx * CDIM + cq + it*8 + 4];
      *(float4*)&quant[(size_t)(t0 + r) * CDIM + cq + it*8]     = v0;
      *(float4*)&quant[(size_t)(t0 + r) * CDIM + cq + it*8 + 4] = v1;
    }
  }
}

// ---------------- launch ----------------------------------------------------
extern "C" void kernel_launch(void* const* d_in, const int* in_sizes, int n_in,
                              void* d_out, int out_size, void* d_ws, size_t ws_size,
                              hipStream_t stream) {
  const float* encode = (const float*)d_in[0];
  const float* cb     = (const float*)d_in[1];
  const float* pw     = (const float*)d_in[2];
  const float* pb     = (const float*)d_in[3];

  float* e   = (float*)d_ws;                              // 4 MB
  float* e2p = e + (size_t)K_CODES * CDIM;                // 64 KB (4 partials)
  unsigned short* Ect = (unsigned short*)(e2p + 4*K_CODES); // 4 MB frag-linear

  float* out     = (float*)d_out;
  float* zidx_f  = out;
  float* quant_f = out + NTOK;

  (void)hipFuncSetAttribute((const void*)score_mfma,
                            hipFuncAttributeMaxDynamicSharedMemorySize, 135680);

  proj_gemm<<<dim3(CDIM/64, K_CODES/64), 512, 0, stream>>>(cb, pw, pb, e, Ect, e2p);
  score_mfma<<<NTOK/128, 512, 135680, stream>>>(encode, Ect, e2p, e, zidx_f, quant_f);
}

// Round 23
// 211.035 us; speedup vs baseline: 1.0947x; 1.0049x over previous
//
#include <hip/hip_runtime.h>
#include <hip/hip_bf16.h>

// QuantiZ: e = codebook[4096,1024] @ proj_w[256,1024]^T + proj_b
//          zidx[t] = argmin_k ||z_t - e_k||, quant[t] = e[zidx[t]]
// d_out FLOAT32: [ zidx as float (32768) | quant (32768*256) ].
// Score GEMM: split-bf16 3-term (hi*hi + hi*lo + lo*hi), 16x16x32 MFMA.
// R23: score_mfma = exact R18/R20 (closed at ~178us, within ~7% of its
//      three-pipe serial budget; all 8 structural levers A/B'd). proj_gemm:
//      split-K=4 (1024 thr = 4 K-groups x 256, acc4x4 16:2 ratio each,
//      deterministic LDS combine) - extends R22's proven mechanism.

#define K_CODES 4096
#define CDIM    256
#define IDIM    1024
#define NTOK    32768

typedef __attribute__((ext_vector_type(8))) short short8;
typedef __attribute__((ext_vector_type(4))) float f32x4;

__device__ __forceinline__ unsigned short f32_to_bf16_rne(float f) {
  union { float f; unsigned int u; } x; x.f = f;
  unsigned int r = x.u + 0x7FFFu + ((x.u >> 16) & 1u);
  return (unsigned short)(r >> 16);
}
__device__ __forceinline__ float bf16_to_f32(unsigned short h) {
  union { unsigned int u; float f; } x; x.u = ((unsigned int)h) << 16;
  return x.f;
}

// ---- Kernel A: e = cb @ pw^T + pb (64x64 tile, split-K=4) ------------------
// 1024 thr = 4 K-groups x 256. Each group: k-major LDS tiles [32][68],
// acc 4x4/thread over K=256. Combine: kg1-3 -> LDS, kg0 adds in fixed order
// (deterministic), kg0 epilogue writes e (f32), fragment-linear Ect, e2p.
// Ect layout: frag(kb 0..15, ct 0..255) = 1024 B at (kb*256+ct)*1024,
// lane lf = g*16 + cl holds k-octet g of code ct*16+cl; kb0-7 hi, 8-15 lo.
extern "C" __global__ __launch_bounds__(1024)
void proj_gemm(const float* __restrict__ cb, const float* __restrict__ pw,
               const float* __restrict__ pb, float* __restrict__ e,
               unsigned short* __restrict__ Ect, float* __restrict__ e2p) {
  extern __shared__ __align__(16) char psmem[];   // 69632 B
  float* AsB = (float*)psmem;                     // [4][32][68]
  float* BsB = (float*)(psmem + 34816);           // [4][32][68]
  const int tid = threadIdx.x;
  const int kg  = tid >> 8;                 // K-group 0..3
  const int t   = tid & 255;
  const int tx  = t & 15, ty = t >> 4;      // 16x16 -> acc 4x4
  const int m0  = blockIdx.y << 6;
  const int n0  = blockIdx.x << 6;
  const int r   = t >> 2;                   // staging row 0..63
  const int c8  = (t & 3) << 3;             // staging col 0,8,16,24
  float* As = AsB + kg * 2176;              // [32][68]
  float* Bs = BsB + kg * 2176;
  float acc[4][4] = {};
  for (int s = 0; s < 8; ++s) {             // 8 steps x 32 k per group
    const int k0 = kg*256 + s*32;
    float4 a0 = *(const float4*)&cb[(size_t)(m0 + r) * IDIM + k0 + c8];
    float4 a1 = *(const float4*)&cb[(size_t)(m0 + r) * IDIM + k0 + c8 + 4];
    float4 b0 = *(const float4*)&pw[(size_t)(n0 + r) * IDIM + k0 + c8];
    float4 b1 = *(const float4*)&pw[(size_t)(n0 + r) * IDIM + k0 + c8 + 4];
    __syncthreads();
    As[(c8+0)*68+r]=a0.x; As[(c8+1)*68+r]=a0.y; As[(c8+2)*68+r]=a0.z; As[(c8+3)*68+r]=a0.w;
    As[(c8+4)*68+r]=a1.x; As[(c8+5)*68+r]=a1.y; As[(c8+6)*68+r]=a1.z; As[(c8+7)*68+r]=a1.w;
    Bs[(c8+0)*68+r]=b0.x; Bs[(c8+1)*68+r]=b0.y; Bs[(c8+2)*68+r]=b0.z; Bs[(c8+3)*68+r]=b0.w;
    Bs[(c8+4)*68+r]=b1.x; Bs[(c8+5)*68+r]=b1.y; Bs[(c8+6)*68+r]=b1.z; Bs[(c8+7)*68+r]=b1.w;
    __syncthreads();
    #pragma unroll
    for (int kk = 0; kk < 32; ++kk) {
      const float4 av = *(const float4*)&As[kk*68 + ty*4];
      const float4 bv = *(const float4*)&Bs[kk*68 + tx*4];
      const float a4[4] = {av.x, av.y, av.z, av.w};
      const float b4[4] = {bv.x, bv.y, bv.z, bv.w};
      #pragma unroll
      for (int i = 0; i < 4; ++i)
        #pragma unroll
        for (int j = 0; j < 4; ++j)
          acc[i][j] += a4[i] * b4[j];
    }
  }
  // combine K-quarters (deterministic: acc0 + g1 + g2 + g3)
  float* Cb = (float*)psmem;                // 48 KB alias, tiles dead
  __syncthreads();
  if (kg > 0) {
    #pragma unroll
    for (int i = 0; i < 4; ++i)
      *(float4*)&Cb[(size_t)(kg-1)*4096 + (ty*4 + i)*64 + tx*4] = *(float4*)&acc[i][0];
  }
  __syncthreads();
  if (kg == 0) {
    const int col0 = n0 + tx*4;
    const int kb   = col0 >> 5;
    const int g    = (col0 >> 3) & 3;
    const int half = (col0 >> 2) & 1;
    float p2[4];
    #pragma unroll
    for (int i = 0; i < 4; ++i) {
      const int row = m0 + ty*4 + i;
      const float4 o1 = *(const float4*)&Cb[          (ty*4 + i)*64 + tx*4];
      const float4 o2 = *(const float4*)&Cb[ 4096 +   (ty*4 + i)*64 + tx*4];
      const float4 o3 = *(const float4*)&Cb[ 8192 +   (ty*4 + i)*64 + tx*4];
      const float o14[4] = {o1.x,o1.y,o1.z,o1.w};
      const float o24[4] = {o2.x,o2.y,o2.z,o2.w};
      const float o34[4] = {o3.x,o3.y,o3.z,o3.w};
      float vv[4];
      unsigned short h4[4], l4[4];
      #pragma unroll
      for (int j = 0; j < 4; ++j) {
        vv[j] = ((acc[i][j] + o14[j]) + o24[j]) + o34[j] + pb[col0 + j];
        h4[j] = f32_to_bf16_rne(vv[j]);
        l4[j] = f32_to_bf16_rne(vv[j] - bf16_to_f32(h4[j]));
      }
      *(float4*)&e[(size_t)row * CDIM + col0] = *(float4*)vv;
      const int ct = row >> 4, cl = row & 15;
      const size_t fi = ((size_t)(kb      * 256 + ct) * 64 + g*16 + cl) * 8 + half*4;
      const size_t fo = ((size_t)((kb+8)  * 256 + ct) * 64 + g*16 + cl) * 8 + half*4;
      *(ushort4*)&Ect[fi] = *(ushort4*)h4;
      *(ushort4*)&Ect[fo] = *(ushort4*)l4;
      p2[i] = vv[0]*vv[0] + vv[1]*vv[1] + vv[2]*vv[2] + vv[3]*vv[3];
    }
    #pragma unroll
    for (int m = 1; m < 16; m <<= 1) {
      #pragma unroll
      for (int i = 0; i < 4; ++i) p2[i] += __shfl_xor(p2[i], m, 64);
    }
    if (tx == 0) {
      #pragma unroll
      for (int i = 0; i < 4; ++i)
        e2p[(size_t)blockIdx.x * K_CODES + m0 + ty*4 + i] = p2[i];
    }
  }
}

// ---------------- Kernel B: MFMA score + argmin + fused gather --------------
// (exact R18/R20 structure) 128 tokens/block, 8 waves = 2 tg x 4 cg.
// Wave = 64 tok x 64 codes (i in 4, jj in 4). Z: 128 frag-linear LDS frags.
// e2 read as sum of 4 deterministic partials.
extern "C" __global__ __launch_bounds__(512, 2)
void score_mfma(const float* __restrict__ z, const unsigned short* __restrict__ Ect,
                const float* __restrict__ e2p, const float* __restrict__ eg,
                float* __restrict__ zidx_f, float* __restrict__ quant) {
  extern __shared__ __align__(16) char smem[];   // 128K Z + 4K red + 512 idx
  char* Zb = smem;

  const int tid = threadIdx.x;
  const int l   = tid & 63;
  const int w   = tid >> 6;          // wave 0..7
  const int tg  = w >> 2;            // token group 0..1
  const int cg  = w & 3;             // code group 0..3
  const int t0  = blockIdx.x << 7;   // 128 tokens per block

  // ---- stage Z (hi/lo bf16) into fragment-linear LDS frags ----
  #pragma unroll
  for (int rr = 0; rr < 2; ++rr) {
    const int r  = rr*64 + (tid >> 3);    // token row 0..127
    const int cq = tid & 7;               // col base cq*32
    const int i8 = r >> 4;                // frag i 0..7
    const int rl = (r & 15) << 4;         // lane-slot byte within frag
    #pragma unroll
    for (int it = 0; it < 4; ++it) {
      const int col = cq*32 + it*8;       // g = it, kb_hi = cq, kb_lo = cq+8
      const float4 v0 = *(const float4*)&z[(size_t)(t0 + r) * CDIM + col];
      const float4 v1 = *(const float4*)&z[(size_t)(t0 + r) * CDIM + col + 4];
      float vv[8] = {v0.x,v0.y,v0.z,v0.w,v1.x,v1.y,v1.z,v1.w};
      unsigned int hp[4], lp[4];
      #pragma unroll
      for (int c = 0; c < 4; ++c) {
        unsigned short h0 = f32_to_bf16_rne(vv[2*c]);
        unsigned short h1 = f32_to_bf16_rne(vv[2*c+1]);
        unsigned short l0 = f32_to_bf16_rne(vv[2*c]   - bf16_to_f32(h0));
        unsigned short l1 = f32_to_bf16_rne(vv[2*c+1] - bf16_to_f32(h1));
        hp[c] = (unsigned int)h0 | ((unsigned int)h1 << 16);
        lp[c] = (unsigned int)l0 | ((unsigned int)l1 << 16);
      }
      const int lane_b = it*256 + rl;     // (g*16 + (r&15)) * 16
      *(uint4*)(Zb + (size_t)(i8*16 + cq    ) * 1024 + lane_b) = *(uint4*)hp;
      *(uint4*)(Zb + (size_t)(i8*16 + cq + 8) * 1024 + lane_b) = *(uint4*)lp;
    }
  }
  __syncthreads();   // Z ready; no further barriers until final reduce

  float bestv[4][4];
  int   besti[4][4];
  #pragma unroll
  for (int i = 0; i < 4; ++i)
    #pragma unroll
    for (int r = 0; r < 4; ++r) { bestv[i][r] = 3.4e38f; besti[i][r] = 0; }

  const int cl = l & 15;
  const int g  = l >> 4;

  // Ect frag(kb, ct) at (kb*256+ct)*1024; wave's ct = cc*16 + cg*4 + jj
  const char* ebase = (const char*)Ect + (size_t)l * 16 + (size_t)cg * 4096;
  // A frags for this wave: frag index (tg*4 + i)*16 + kb
  const char* Zl    = Zb + (size_t)l * 16 + (size_t)tg * 65536;

  // pipeline registers (depth-1), carried across cc
  short8 aHc[4], aLc[4], bHc[4], bLc[4];
  #pragma unroll
  for (int i = 0; i < 4; ++i) {
    aHc[i] = *(const short8*)(Zl + (size_t)(i*16 + 0) * 1024);
    aLc[i] = *(const short8*)(Zl + (size_t)(i*16 + 8) * 1024);
  }
  #pragma unroll
  for (int jj = 0; jj < 4; ++jj) {
    bHc[jj] = *(const short8*)(ebase + (size_t)0 * 262144 + jj * 1024);
    bLc[jj] = *(const short8*)(ebase + (size_t)8 * 262144 + jj * 1024);
  }

  for (int cc = 0; cc < 16; ++cc) {              // 256-code chunks
    const char* ecc  = ebase + (size_t)cc * 16384;
    const char* eccn = ebase + (size_t)((cc + 1) & 15) * 16384;

    f32x4 acc[4][4];
    #pragma unroll
    for (int i = 0; i < 4; ++i)
      #pragma unroll
      for (int jj = 0; jj < 4; ++jj) acc[i][jj] = (f32x4){0.f,0.f,0.f,0.f};

    float e2v[4];
    #pragma unroll
    for (int jj = 0; jj < 4; ++jj) {
      const int code = cc*256 + cg*64 + jj*16 + cl;
      e2v[jj] = e2p[code] + e2p[K_CODES + code]
              + e2p[2*K_CODES + code] + e2p[3*K_CODES + code];
    }

    #pragma unroll
    for (int kw = 0; kw < 8; ++kw) {
      // issue next step's loads (B global first, then A ds)
      short8 aHn[4], aLn[4], bHn[4], bLn[4];
      {
        const char* bsrc = (kw < 7) ? ecc : eccn;
        const int kwn = (kw + 1) & 7;
        #pragma unroll
        for (int jj = 0; jj < 4; ++jj) {
          bHn[jj] = *(const short8*)(bsrc + (size_t)(kwn    ) * 262144 + jj * 1024);
          bLn[jj] = *(const short8*)(bsrc + (size_t)(kwn + 8) * 262144 + jj * 1024);
        }
        #pragma unroll
        for (int i = 0; i < 4; ++i) {
          aHn[i] = *(const short8*)(Zl + (size_t)(i*16 + kwn    ) * 1024);
          aLn[i] = *(const short8*)(Zl + (size_t)(i*16 + kwn + 8) * 1024);
        }
      }
      __builtin_amdgcn_s_setprio(1);   // fence bounds hoist window (R15)
      #pragma unroll
      for (int i = 0; i < 4; ++i)
        #pragma unroll
        for (int jj = 0; jj < 4; ++jj)
          acc[i][jj] = __builtin_amdgcn_mfma_f32_16x16x32_bf16(aHc[i], bHc[jj], acc[i][jj], 0, 0, 0);
      #pragma unroll
      for (int i = 0; i < 4; ++i)
        #pragma unroll
        for (int jj = 0; jj < 4; ++jj)
          acc[i][jj] = __builtin_amdgcn_mfma_f32_16x16x32_bf16(aHc[i], bLc[jj], acc[i][jj], 0, 0, 0);
      #pragma unroll
      for (int i = 0; i < 4; ++i)
        #pragma unroll
        for (int jj = 0; jj < 4; ++jj)
          acc[i][jj] = __builtin_amdgcn_mfma_f32_16x16x32_bf16(aLc[i], bHc[jj], acc[i][jj], 0, 0, 0);
      __builtin_amdgcn_s_setprio(0);
      // rename pipeline regs
      #pragma unroll
      for (int i = 0; i < 4; ++i) { aHc[i] = aHn[i]; aLc[i] = aLn[i]; }
      #pragma unroll
      for (int jj = 0; jj < 4; ++jj) { bHc[jj] = bHn[jj]; bLc[jj] = bLn[jj]; }
    }
    // epilogue: scores -> running argmin (codes ascend: cc outer, jj inner)
    #pragma unroll
    for (int jj = 0; jj < 4; ++jj) {
      const int code = cc*256 + cg*64 + jj*16 + cl;
      #pragma unroll
      for (int i = 0; i < 4; ++i)
        #pragma unroll
        for (int r = 0; r < 4; ++r) {
          const float sc = e2v[jj] - 2.0f * acc[i][jj][r];
          if (sc < bestv[i][r]) { bestv[i][r] = sc; besti[i][r] = code; }
        }
    }
  }

  // ---- final argmin reduce: 16 code-lanes, then 4 cg waves via LDS ----
  struct RP { float v; int i; };
  RP*  red    = (RP*)(smem + 131072);          // [128][4]
  int* sh_idx = (int*)(smem + 131072 + 4096);  // [128]
  #pragma unroll
  for (int i = 0; i < 4; ++i)
    #pragma unroll
    for (int r = 0; r < 4; ++r) {
      float v = bestv[i][r]; int bi = besti[i][r];
      #pragma unroll
      for (int m = 1; m < 16; m <<= 1) {
        const float ov = __shfl_xor(v, m, 64);
        const int   oi = __shfl_xor(bi, m, 64);
        if (ov < v || (ov == v && oi < bi)) { v = ov; bi = oi; }
      }
      if (cl == 0) {                 // lanes 0,16,32,48 own token tg*64+i*16+g*4+r
        const int tl = tg*64 + i*16 + g*4 + r;
        red[tl*4 + cg].v = v; red[tl*4 + cg].i = bi;
      }
    }
  __syncthreads();
  if (tid < 128) {
    float v = red[tid*4].v; int bi = red[tid*4].i;
    #pragma unroll
    for (int x = 1; x < 4; ++x) {
      const float ov = red[tid*4 + x].v; const int oi = red[tid*4 + x].i;
      if (ov < v || (ov == v && oi < bi)) { v = ov; bi = oi; }
    }
    zidx_f[t0 + tid] = (float)bi;
    sh_idx[tid] = bi;
  }
  __syncthreads();

  // ---- fused gather: quant[t] = e[idx[t]] (f32, e is L2-resident) ----
  #pragma unroll
  for (int rr = 0; rr < 2; ++rr) {
    const int r   = rr*64 + (tid >> 3);    // token row 0..127
    const int cq  = (tid & 7) << 5;        // col base 0..224
    const int idx = sh_idx[r];
    #pragma unroll
    for (int it = 0; it < 4; ++it) {
      const float4 v0 = *(const float4*)&eg[(size_t)idx * CDIM + cq + it*8];
      const float4 v1 = *(const float4*)&eg[(size_t)idx * CDIM + cq + it*8 + 4];
      *(float4*)&quant[(size_t)(t0 + r) * CDIM + cq + it*8]     = v0;
      *(float4*)&quant[(size_t)(t0 + r) * CDIM + cq + it*8 + 4] = v1;
    }
  }
}

// ---------------- launch ----------------------------------------------------
extern "C" void kernel_launch(void* const* d_in, const int* in_sizes, int n_in,
                              void* d_out, int out_size, void* d_ws, size_t ws_size,
                              hipStream_t stream) {
  const float* encode = (const float*)d_in[0];
  const float* cb     = (const float*)d_in[1];
  const float* pw     = (const float*)d_in[2];
  const float* pb     = (const float*)d_in[3];

  float* e   = (float*)d_ws;                              // 4 MB
  float* e2p = e + (size_t)K_CODES * CDIM;                // 64 KB (4 partials)
  unsigned short* Ect = (unsigned short*)(e2p + 4*K_CODES); // 4 MB frag-linear

  float* out     = (float*)d_out;
  float* zidx_f  = out;
  float* quant_f = out + NTOK;

  (void)hipFuncSetAttribute((const void*)proj_gemm,
                            hipFuncAttributeMaxDynamicSharedMemorySize, 69632);
  (void)hipFuncSetAttribute((const void*)score_mfma,
                            hipFuncAttributeMaxDynamicSharedMemorySize, 135680);

  proj_gemm<<<dim3(CDIM/64, K_CODES/64), 1024, 69632, stream>>>(cb, pw, pb, e, Ect, e2p);
  score_mfma<<<NTOK/128, 512, 135680, stream>>>(encode, Ect, e2p, e, zidx_f, quant_f);
}